// Round 1
// baseline (2466.749 us; speedup 1.0000x reference)
//
#include <hip/hip_runtime.h>
#include <stdint.h>

typedef unsigned int u32;
typedef unsigned short u16;

#define C_   256
#define C8_  32
#define H_   128
#define W_   128
#define HW_  (H_*W_)

__device__ __forceinline__ float bf2f(u32 u) {
    union { u32 i; float f; } v; v.i = u << 16; return v.f;
}
__device__ __forceinline__ u16 f2bf(float f) {
    union { float f; u32 i; } v; v.f = f;
    u32 r = v.i + 0x7fffu + ((v.i >> 16) & 1u);
    return (u16)(r >> 16);
}

// ---------------------------------------------------------------------------
// PAM1: B=512 (n,ph,pw), L=256 (qh*16+qw), xf1[b,c,l] = x[n,c,qh*8+ph,qw*8+pw]
// PAM2: B=2048 (n,qh,qw), L=64 (ph*8+pw)
// ---------------------------------------------------------------------------

// K1: fb1/fc1 [512,32,256]  (fp32)
__global__ __launch_bounds__(256) void k_fbfc1(
    const float* __restrict__ x, const float* __restrict__ Wb,
    const float* __restrict__ bb, const float* __restrict__ Wc,
    const float* __restrict__ bc, float* __restrict__ fb, float* __restrict__ fc)
{
    __shared__ __align__(16) float xt[C_ * 32];
    const int tile = blockIdx.x;   // l1-tile of 32
    const int b = blockIdx.y;
    const int t = threadIdx.x;
    const int n = b >> 6, ph = (b >> 3) & 7, pw = b & 7;
    const float* xb = x + (size_t)n * C_ * HW_;
    #pragma unroll
    for (int s = 0; s < 32; ++s) {
        int i = t + 256 * s;
        int c = i >> 5, l = i & 31;
        int l1 = tile * 32 + l;
        int qh = l1 >> 4, qw = l1 & 15;
        xt[c * 32 + l] = xb[(size_t)c * HW_ + (qh * 8 + ph) * W_ + (qw * 8 + pw)];
    }
    __syncthreads();
    const int l = t & 31;
    const int og = t >> 5;            // 0..7
    const float* Wp = (og < 4) ? Wb : Wc;
    const float* bp = (og < 4) ? bb : bc;
    float* op = (og < 4) ? fb : fc;
    const int ob = (og & 3) * 8;
    float acc[8];
    #pragma unroll
    for (int j = 0; j < 8; ++j) acc[j] = bp[ob + j];
    for (int c = 0; c < C_; ++c) {
        float xv = xt[c * 32 + l];
        #pragma unroll
        for (int j = 0; j < 8; ++j)
            acc[j] += Wp[(ob + j) * C_ + c] * xv;
    }
    #pragma unroll
    for (int j = 0; j < 8; ++j)
        op[((size_t)b * C8_ + ob + j) * 256 + tile * 32 + l] = acc[j];
}

// K2: fd1 [512,256,256] (bf16)
__global__ __launch_bounds__(256) void k_fd1(
    const float* __restrict__ x, const float* __restrict__ Wd,
    const float* __restrict__ bd, u16* __restrict__ fd)
{
    __shared__ __align__(16) float xt[C_ * 32];
    const int tile = blockIdx.x, b = blockIdx.y, t = threadIdx.x;
    const int n = b >> 6, ph = (b >> 3) & 7, pw = b & 7;
    const float* xb = x + (size_t)n * C_ * HW_;
    #pragma unroll
    for (int s = 0; s < 32; ++s) {
        int i = t + 256 * s;
        int k = i >> 5, m = i & 31;
        int l1 = tile * 32 + m;
        int qh = l1 >> 4, qw = l1 & 15;
        xt[k * 32 + m] = xb[(size_t)k * HW_ + (qh * 8 + ph) * W_ + (qw * 8 + pw)];
    }
    __syncthreads();
    const int c = t;
    float acc[32];
    #pragma unroll
    for (int m = 0; m < 32; ++m) acc[m] = 0.f;
    const float* wrow = Wd + c * C_;
    for (int k = 0; k < C_; k += 4) {
        float4 w = *(const float4*)(wrow + k);
        float wk[4] = {w.x, w.y, w.z, w.w};
        #pragma unroll
        for (int kk = 0; kk < 4; ++kk) {
            const float4* xr = (const float4*)(xt + (k + kk) * 32);
            float wv = wk[kk];
            #pragma unroll
            for (int q = 0; q < 8; ++q) {
                float4 xv = xr[q];
                acc[q*4+0] += wv * xv.x;
                acc[q*4+1] += wv * xv.y;
                acc[q*4+2] += wv * xv.z;
                acc[q*4+3] += wv * xv.w;
            }
        }
    }
    const float bdv = bd[c];
    u32* dst = (u32*)(fd + ((size_t)b * C_ + c) * 256 + tile * 32);
    #pragma unroll
    for (int m = 0; m < 16; ++m) {
        u32 lo = f2bf(acc[2*m] + bdv);
        u32 hi = f2bf(acc[2*m+1] + bdv);
        dst[m] = lo | (hi << 16);
    }
}

// K3: attn1 + fe1 + residual -> xf2 (bf16, PAM2 layout)
__global__ __launch_bounds__(256) void k_attn_fe1(
    const float* __restrict__ x, const float* __restrict__ fb,
    const float* __restrict__ fc, const u16* __restrict__ fd,
    const float* __restrict__ alpha, u16* __restrict__ xf2)
{
    __shared__ __align__(16) float smem[12800];
    float* fbt = smem;            // [32][16] (o,l)
    float* fct = smem + 512;      // [32][256] (o,m)
    float* S   = smem + 8704;     // [16][256] (l,m)
    float* attnT = smem + 512;    // [256][16] (m,l) overlays fct (dead after S)
    const int tile = blockIdx.x;  // l1-tile of 16
    const int b = blockIdx.y, t = threadIdx.x;
    #pragma unroll
    for (int s = 0; s < 2; ++s) {
        int j = t + 256 * s;
        int o = j >> 4, l = j & 15;
        fbt[o * 16 + l] = fb[((size_t)b * C8_ + o) * 256 + tile * 16 + l];
    }
    #pragma unroll
    for (int s = 0; s < 32; ++s) {
        int j = t + 256 * s;
        int o = j >> 8, m = j & 255;
        fct[o * 256 + m] = fc[((size_t)b * C8_ + o) * 256 + m];
    }
    __syncthreads();
    {   // S[l][m] = sum_o fbt[o][l]*fct[o][m]
        const int lane = t & 63, wv = t >> 6;
        float acc[4][4];
        #pragma unroll
        for (int i = 0; i < 4; ++i)
            #pragma unroll
            for (int j = 0; j < 4; ++j) acc[i][j] = 0.f;
        for (int o = 0; o < 32; ++o) {
            float cv[4];
            #pragma unroll
            for (int j = 0; j < 4; ++j) cv[j] = fct[o * 256 + lane + 64 * j];
            #pragma unroll
            for (int i = 0; i < 4; ++i) {
                float a = fbt[o * 16 + wv * 4 + i];
                #pragma unroll
                for (int j = 0; j < 4; ++j) acc[i][j] += a * cv[j];
            }
        }
        #pragma unroll
        for (int i = 0; i < 4; ++i)
            #pragma unroll
            for (int j = 0; j < 4; ++j)
                S[(wv * 4 + i) * 256 + lane + 64 * j] = acc[i][j];
    }
    __syncthreads();
    {   // softmax rows of S (16 rows, 16 threads/row), write attnT[m][l]
        const int r = t >> 4, k = t & 15;
        float vals[16];
        float mx = -1e30f;
        #pragma unroll
        for (int j = 0; j < 16; ++j) {
            vals[j] = S[r * 256 + k + 16 * j];
            mx = fmaxf(mx, vals[j]);
        }
        mx = fmaxf(mx, __shfl_xor(mx, 1, 16));
        mx = fmaxf(mx, __shfl_xor(mx, 2, 16));
        mx = fmaxf(mx, __shfl_xor(mx, 4, 16));
        mx = fmaxf(mx, __shfl_xor(mx, 8, 16));
        float sum = 0.f;
        #pragma unroll
        for (int j = 0; j < 16; ++j) { vals[j] = __expf(vals[j] - mx); sum += vals[j]; }
        sum += __shfl_xor(sum, 1, 16);
        sum += __shfl_xor(sum, 2, 16);
        sum += __shfl_xor(sum, 4, 16);
        sum += __shfl_xor(sum, 8, 16);
        const float inv = 1.0f / sum;
        #pragma unroll
        for (int j = 0; j < 16; ++j)
            attnT[(k + 16 * j) * 16 + r] = vals[j] * inv;
    }
    __syncthreads();
    // fe[c][l], c = t; out1 = alpha*fe + xf1 -> scatter to xf2 (PAM2 layout)
    const int c = t;
    float acc[16];
    #pragma unroll
    for (int i = 0; i < 16; ++i) acc[i] = 0.f;
    const u16* fdrow = fd + ((size_t)b * C_ + c) * 256;
    for (int m = 0; m < 256; m += 4) {
        uint2 p = *(const uint2*)(fdrow + m);
        float wm[4] = { bf2f(p.x & 0xffffu), bf2f(p.x >> 16),
                        bf2f(p.y & 0xffffu), bf2f(p.y >> 16) };
        #pragma unroll
        for (int mm = 0; mm < 4; ++mm) {
            const float4* ar = (const float4*)(attnT + (m + mm) * 16);
            float wv = wm[mm];
            #pragma unroll
            for (int q = 0; q < 4; ++q) {
                float4 av = ar[q];
                acc[q*4+0] += wv * av.x;
                acc[q*4+1] += wv * av.y;
                acc[q*4+2] += wv * av.z;
                acc[q*4+3] += wv * av.w;
            }
        }
    }
    const float al = alpha[0];
    const int n = b >> 6, ph = (b >> 3) & 7, pw = b & 7;
    const int l2 = ph * 8 + pw;
    const float* xb = x + (size_t)n * C_ * HW_ + (size_t)c * HW_;
    #pragma unroll
    for (int i = 0; i < 16; ++i) {
        int l1 = tile * 16 + i;
        int qh = l1 >> 4, qw = l1 & 15;
        float xv = xb[(qh * 8 + ph) * W_ + (qw * 8 + pw)];
        int b2 = (n * 16 + qh) * 16 + qw;
        xf2[((size_t)b2 * C_ + c) * 64 + l2] = f2bf(al * acc[i] + xv);
    }
}

// K4: fb2/fc2 [2048,32,64] (fp32)
__global__ __launch_bounds__(256) void k_fbfc2(
    const u16* __restrict__ xf2, const float* __restrict__ Wb,
    const float* __restrict__ bb, const float* __restrict__ Wc,
    const float* __restrict__ bc, float* __restrict__ fb, float* __restrict__ fc)
{
    __shared__ __align__(16) u16 xt[C_ * 64];
    const int b = blockIdx.x, t = threadIdx.x;
    const u32* src = (const u32*)(xf2 + (size_t)b * C_ * 64);
    u32* dst = (u32*)xt;
    #pragma unroll
    for (int s = 0; s < 32; ++s) dst[t + 256 * s] = src[t + 256 * s];
    __syncthreads();
    const int l = t & 63, og = t >> 6;   // 0..3
    const float* Wp = (og < 2) ? Wb : Wc;
    const float* bp = (og < 2) ? bb : bc;
    float* op = (og < 2) ? fb : fc;
    const int ob = (og & 1) * 16;
    float acc[16];
    #pragma unroll
    for (int j = 0; j < 16; ++j) acc[j] = bp[ob + j];
    for (int c = 0; c < C_; ++c) {
        float xv = bf2f(xt[c * 64 + l]);
        #pragma unroll
        for (int j = 0; j < 16; ++j)
            acc[j] += Wp[(ob + j) * C_ + c] * xv;
    }
    #pragma unroll
    for (int j = 0; j < 16; ++j)
        op[((size_t)b * C8_ + ob + j) * 64 + l] = acc[j];
}

// K5: fd2 [2048,256,64] (bf16)
__global__ __launch_bounds__(256) void k_fd2(
    const u16* __restrict__ xf2, const float* __restrict__ Wd,
    const float* __restrict__ bd, u16* __restrict__ fd)
{
    __shared__ __align__(16) float xt[C_ * 32];
    const int mt = blockIdx.x & 1;
    const int b = blockIdx.x >> 1;
    const int t = threadIdx.x;
    const u32* src = (const u32*)(xf2 + (size_t)b * C_ * 64);
    #pragma unroll
    for (int s = 0; s < 16; ++s) {
        int j = t + 256 * s;
        int k = j >> 4, mp = j & 15;
        u32 u = src[k * 32 + mt * 16 + mp];
        xt[k * 32 + mp * 2]     = bf2f(u & 0xffffu);
        xt[k * 32 + mp * 2 + 1] = bf2f(u >> 16);
    }
    __syncthreads();
    const int c = t;
    float acc[32];
    #pragma unroll
    for (int m = 0; m < 32; ++m) acc[m] = 0.f;
    const float* wrow = Wd + c * C_;
    for (int k = 0; k < C_; k += 4) {
        float4 w = *(const float4*)(wrow + k);
        float wk[4] = {w.x, w.y, w.z, w.w};
        #pragma unroll
        for (int kk = 0; kk < 4; ++kk) {
            const float4* xr = (const float4*)(xt + (k + kk) * 32);
            float wv = wk[kk];
            #pragma unroll
            for (int q = 0; q < 8; ++q) {
                float4 xv = xr[q];
                acc[q*4+0] += wv * xv.x;
                acc[q*4+1] += wv * xv.y;
                acc[q*4+2] += wv * xv.z;
                acc[q*4+3] += wv * xv.w;
            }
        }
    }
    const float bdv = bd[c];
    u32* dstp = (u32*)(fd + ((size_t)b * C_ + c) * 64 + mt * 32);
    #pragma unroll
    for (int m = 0; m < 16; ++m) {
        u32 lo = f2bf(acc[2*m] + bdv);
        u32 hi = f2bf(acc[2*m+1] + bdv);
        dstp[m] = lo | (hi << 16);
    }
}

// K6: attn2 + fe2 + residual -> out (fp32, NCHW)
__global__ __launch_bounds__(256) void k_attn_fe2(
    const u16* __restrict__ xf2, const float* __restrict__ fb,
    const float* __restrict__ fc, const u16* __restrict__ fd,
    const float* __restrict__ alpha, float* __restrict__ out)
{
    __shared__ __align__(16) float smem[12544];
    float* fbt = smem;           // [32][64]
    float* fct = smem + 2048;    // [32][64]
    float* S   = smem + 4096;    // [64][64]
    float* attnT = smem + 8192;  // [64][68] (m,l) padded
    const int b = blockIdx.x, t = threadIdx.x;
    #pragma unroll
    for (int s = 0; s < 8; ++s) {
        int j = t + 256 * s;
        int o = j >> 6, l = j & 63;
        fbt[o * 64 + l] = fb[((size_t)b * C8_ + o) * 64 + l];
        fct[o * 64 + l] = fc[((size_t)b * C8_ + o) * 64 + l];
    }
    __syncthreads();
    {
        const int lane = t & 63, wv = t >> 6;
        float acc[16];
        #pragma unroll
        for (int i = 0; i < 16; ++i) acc[i] = 0.f;
        for (int o = 0; o < 32; ++o) {
            float cv = fct[o * 64 + lane];
            #pragma unroll
            for (int i = 0; i < 16; ++i)
                acc[i] += fbt[o * 64 + wv * 16 + i] * cv;
        }
        #pragma unroll
        for (int i = 0; i < 16; ++i)
            S[(wv * 16 + i) * 64 + lane] = acc[i];
    }
    __syncthreads();
    {
        const int r = t >> 2, k = t & 3;
        float vals[16];
        float mx = -1e30f;
        #pragma unroll
        for (int j = 0; j < 16; ++j) {
            vals[j] = S[r * 64 + k + 4 * j];
            mx = fmaxf(mx, vals[j]);
        }
        mx = fmaxf(mx, __shfl_xor(mx, 1, 4));
        mx = fmaxf(mx, __shfl_xor(mx, 2, 4));
        float sum = 0.f;
        #pragma unroll
        for (int j = 0; j < 16; ++j) { vals[j] = __expf(vals[j] - mx); sum += vals[j]; }
        sum += __shfl_xor(sum, 1, 4);
        sum += __shfl_xor(sum, 2, 4);
        const float inv = 1.0f / sum;
        #pragma unroll
        for (int j = 0; j < 16; ++j)
            attnT[(k + 4 * j) * 68 + r] = vals[j] * inv;
    }
    __syncthreads();
    const int c = t;
    const float al = alpha[0];
    const int n = b >> 8, qh = (b >> 4) & 15, qw = b & 15;
    const u16* fdrow = fd + ((size_t)b * C_ + c) * 64;
    const u16* xrow  = xf2 + ((size_t)b * C_ + c) * 64;
    float* orow = out + ((size_t)n * C_ + c) * HW_;
    for (int half = 0; half < 2; ++half) {
        float acc[32];
        #pragma unroll
        for (int i = 0; i < 32; ++i) acc[i] = 0.f;
        for (int m = 0; m < 64; m += 4) {
            uint2 p = *(const uint2*)(fdrow + m);
            float wm[4] = { bf2f(p.x & 0xffffu), bf2f(p.x >> 16),
                            bf2f(p.y & 0xffffu), bf2f(p.y >> 16) };
            #pragma unroll
            for (int mm = 0; mm < 4; ++mm) {
                const float4* ar = (const float4*)(attnT + (m + mm) * 68 + half * 32);
                float wv = wm[mm];
                #pragma unroll
                for (int q = 0; q < 8; ++q) {
                    float4 av = ar[q];
                    acc[q*4+0] += wv * av.x;
                    acc[q*4+1] += wv * av.y;
                    acc[q*4+2] += wv * av.z;
                    acc[q*4+3] += wv * av.w;
                }
            }
        }
        #pragma unroll
        for (int i = 0; i < 32; ++i) {
            int l = half * 32 + i;
            int ph = l >> 3, pw = l & 7;
            orow[(qh * 8 + ph) * W_ + (qw * 8 + pw)] = al * acc[i] + bf2f(xrow[l]);
        }
    }
}

extern "C" void kernel_launch(void* const* d_in, const int* in_sizes, int n_in,
                              void* d_out, int out_size, void* d_ws, size_t ws_size,
                              hipStream_t stream)
{
    const float* x   = (const float*)d_in[0];
    const float* Wb1 = (const float*)d_in[1];
    const float* bb1 = (const float*)d_in[2];
    const float* Wc1 = (const float*)d_in[3];
    const float* bc1 = (const float*)d_in[4];
    const float* Wd1 = (const float*)d_in[5];
    const float* bd1 = (const float*)d_in[6];
    const float* a1  = (const float*)d_in[7];
    const float* Wb2 = (const float*)d_in[8];
    const float* bb2 = (const float*)d_in[9];
    const float* Wc2 = (const float*)d_in[10];
    const float* bc2 = (const float*)d_in[11];
    const float* Wd2 = (const float*)d_in[12];
    const float* bd2 = (const float*)d_in[13];
    const float* a2  = (const float*)d_in[14];
    (void)in_sizes; (void)n_in; (void)out_size; (void)ws_size;

    char* ws = (char*)d_ws;
    float* fb  = (float*)(ws);                       // 16 MiB fp32 [B][32][L]
    float* fc  = (float*)(ws + 16777216);            // 16 MiB fp32
    u16*   fd  = (u16*)(ws + 33554432);              // 64 MiB bf16 [B][256][L]
    u16*   xf2 = (u16*)(ws + 100663296);             // 64 MiB bf16 [2048][256][64]
    float* out = (float*)d_out;

    k_fbfc1<<<dim3(8, 512), 256, 0, stream>>>(x, Wb1, bb1, Wc1, bc1, fb, fc);
    k_fd1<<<dim3(8, 512), 256, 0, stream>>>(x, Wd1, bd1, fd);
    k_attn_fe1<<<dim3(16, 512), 256, 0, stream>>>(x, fb, fc, fd, a1, xf2);
    k_fbfc2<<<dim3(2048), 256, 0, stream>>>(xf2, Wb2, bb2, Wc2, bc2, fb, fc);
    k_fd2<<<dim3(4096), 256, 0, stream>>>(xf2, Wd2, bd2, fd);
    k_attn_fe2<<<dim3(2048), 256, 0, stream>>>(xf2, fb, fc, fd, a2, out);
}

// Round 2
// 413.053 us; speedup vs baseline: 5.9720x; 5.9720x over previous
//
#include <hip/hip_runtime.h>
#include <stdint.h>

typedef unsigned int u32;
typedef unsigned short u16;

#define C_   256
#define C8_  32
#define H_   128
#define W_   128
#define HW_  (H_*W_)

typedef __bf16 bf16x8_t __attribute__((ext_vector_type(8)));
typedef float  f32x4_t  __attribute__((ext_vector_type(4)));

__device__ __forceinline__ float bf2f(u32 u) {
    union { u32 i; float f; } v; v.i = u << 16; return v.f;
}
__device__ __forceinline__ u16 f2bf(float f) {
    union { float f; u32 i; } v; v.f = f;
    u32 r = v.i + 0x7fffu + ((v.i >> 16) & 1u);
    return (u16)(r >> 16);
}
__device__ __forceinline__ bf16x8_t ld_frag(const u16* p) {
    union { uint4 u; bf16x8_t b; } x; x.u = *(const uint4*)p; return x.b;
}

// ws layout (bytes)
#define WS_XF1   0                  // bf16 [512][256][256]  = 67108864
#define WS_XF2   67108864           // bf16 [2048][64][256]  = 67108864
#define WS_WBC2  134217728          // bf16 [64][256]        = 32768
#define WS_WD2   (134217728+32768)  // bf16 [256][256]       = 131072
#define WS_GEN   134479872          // general path scratch (only touched if alpha1 != 0)
#define WS_FB1   WS_GEN                       // fp32 [512][32][256] = 16777216
#define WS_FC1   (WS_GEN + 16777216)          // fp32 [512][32][256] = 16777216
#define WS_FD1   (WS_GEN + 33554432)          // bf16 [512][256][256] = 67108864

// ---------------------------------------------------------------------------
// Kw: pack PAM2 weights to bf16. Wbc2 rows 0..31 = Wb2, 32..63 = Wc2.
// ---------------------------------------------------------------------------
__global__ __launch_bounds__(256) void k_wpack(
    const float* __restrict__ Wb2, const float* __restrict__ Wc2,
    const float* __restrict__ Wd2, u16* __restrict__ Wbc2, u16* __restrict__ Wd2b)
{
    int gid = blockIdx.x * 256 + threadIdx.x;
    if (gid < 16384) {
        int o = gid >> 8, c = gid & 255;
        float v = (o < 32) ? Wb2[o*256 + c] : Wc2[(o-32)*256 + c];
        Wbc2[gid] = f2bf(v);
    } else if (gid < 81920) {
        Wd2b[gid - 16384] = f2bf(Wd2[gid - 16384]);
    }
}

// ---------------------------------------------------------------------------
// K0: gather/transpose x (fp32 NCHW) -> xf1 bf16 [b1=(n,ph,pw)][l1=(qh,qw)][c]
// and, when alpha1 == 0 (out1 == xf1), also write xf2 bf16 [b2=(n,qh,qw)][l2=(ph,pw)][c]
// block: (n, h, c-half); LDS tile transpose for coalesced writes.
// ---------------------------------------------------------------------------
__global__ __launch_bounds__(256) void k_gather(
    const float* __restrict__ x, const float* __restrict__ alpha1,
    u16* __restrict__ xf1, u16* __restrict__ xf2)
{
    __shared__ __align__(16) u16 xt[128 * 130];
    int id = blockIdx.x;
    int n = id >> 8, h = (id >> 1) & 127, ch = id & 1;
    int qh = h >> 3, ph = h & 7;
    const float* xb = x + (((size_t)(n*256 + ch*128)) * 128 + h) * 128;
    #pragma unroll
    for (int s = 0; s < 16; ++s) {
        int idx = threadIdx.x + 256 * s;     // 0..4095
        int cc = idx >> 5, w4 = idx & 31;
        float4 v = *(const float4*)(xb + (size_t)cc * HW_ + w4 * 4);
        u32 p0 = (u32)f2bf(v.x) | ((u32)f2bf(v.y) << 16);
        u32 p1 = (u32)f2bf(v.z) | ((u32)f2bf(v.w) << 16);
        ((u32*)xt)[cc * 65 + w4 * 2]     = p0;
        ((u32*)xt)[cc * 65 + w4 * 2 + 1] = p1;
    }
    __syncthreads();
    int t = threadIdx.x;
    int r = t & 127, seg = t >> 7;         // r -> (qw,pw); seg -> c-half of half
    int qw = r >> 3, pw = r & 7;
    int wcol = qw * 8 + pw;
    u32 buf[32];
    #pragma unroll
    for (int k = 0; k < 32; ++k) {
        u16 a = xt[(seg * 64 + 2 * k)     * 130 + wcol];
        u16 b = xt[(seg * 64 + 2 * k + 1) * 130 + wcol];
        buf[k] = (u32)a | ((u32)b << 16);
    }
    size_t b1 = (size_t)n * 64 + ph * 8 + pw;
    size_t l1 = qh * 16 + qw;
    u32* d1 = (u32*)(xf1 + (b1 * 256 + l1) * 256 + ch * 128 + seg * 64);
    #pragma unroll
    for (int k = 0; k < 32; ++k) d1[k] = buf[k];
    if (alpha1[0] == 0.f) {
        size_t b2 = (size_t)n * 256 + qh * 16 + qw;
        size_t l2 = ph * 8 + pw;
        u32* d2 = (u32*)(xf2 + (b2 * 64 + l2) * 256 + ch * 128 + seg * 64);
        #pragma unroll
        for (int k = 0; k < 32; ++k) d2[k] = buf[k];
    }
}

// ---------------------------------------------------------------------------
// General-path PAM1 kernels (only execute when alpha1 != 0; validated in R0).
// ---------------------------------------------------------------------------
__global__ __launch_bounds__(256) void k_fbfc1(
    const float* __restrict__ x, const float* __restrict__ Wb,
    const float* __restrict__ bb, const float* __restrict__ Wc,
    const float* __restrict__ bc, float* __restrict__ fb, float* __restrict__ fc,
    const float* __restrict__ alpha)
{
    if (alpha[0] == 0.f) return;
    __shared__ __align__(16) float xt[C_ * 32];
    const int tile = blockIdx.x;
    const int b = blockIdx.y;
    const int t = threadIdx.x;
    const int n = b >> 6, ph = (b >> 3) & 7, pw = b & 7;
    const float* xb = x + (size_t)n * C_ * HW_;
    #pragma unroll
    for (int s = 0; s < 32; ++s) {
        int i = t + 256 * s;
        int c = i >> 5, l = i & 31;
        int l1 = tile * 32 + l;
        int qh = l1 >> 4, qw = l1 & 15;
        xt[c * 32 + l] = xb[(size_t)c * HW_ + (qh * 8 + ph) * W_ + (qw * 8 + pw)];
    }
    __syncthreads();
    const int l = t & 31;
    const int og = t >> 5;
    const float* Wp = (og < 4) ? Wb : Wc;
    const float* bp = (og < 4) ? bb : bc;
    float* op = (og < 4) ? fb : fc;
    const int ob = (og & 3) * 8;
    float acc[8];
    #pragma unroll
    for (int j = 0; j < 8; ++j) acc[j] = bp[ob + j];
    for (int c = 0; c < C_; ++c) {
        float xv = xt[c * 32 + l];
        #pragma unroll
        for (int j = 0; j < 8; ++j)
            acc[j] += Wp[(ob + j) * C_ + c] * xv;
    }
    #pragma unroll
    for (int j = 0; j < 8; ++j)
        op[((size_t)b * C8_ + ob + j) * 256 + tile * 32 + l] = acc[j];
}

__global__ __launch_bounds__(256) void k_fd1(
    const float* __restrict__ x, const float* __restrict__ Wd,
    const float* __restrict__ bd, u16* __restrict__ fd,
    const float* __restrict__ alpha)
{
    if (alpha[0] == 0.f) return;
    __shared__ __align__(16) float xt[C_ * 32];
    const int tile = blockIdx.x, b = blockIdx.y, t = threadIdx.x;
    const int n = b >> 6, ph = (b >> 3) & 7, pw = b & 7;
    const float* xb = x + (size_t)n * C_ * HW_;
    #pragma unroll
    for (int s = 0; s < 32; ++s) {
        int i = t + 256 * s;
        int k = i >> 5, m = i & 31;
        int l1 = tile * 32 + m;
        int qh = l1 >> 4, qw = l1 & 15;
        xt[k * 32 + m] = xb[(size_t)k * HW_ + (qh * 8 + ph) * W_ + (qw * 8 + pw)];
    }
    __syncthreads();
    const int c = t;
    float acc[32];
    #pragma unroll
    for (int m = 0; m < 32; ++m) acc[m] = 0.f;
    const float* wrow = Wd + c * C_;
    for (int k = 0; k < C_; k += 4) {
        float4 w = *(const float4*)(wrow + k);
        float wk[4] = {w.x, w.y, w.z, w.w};
        #pragma unroll
        for (int kk = 0; kk < 4; ++kk) {
            const float4* xr = (const float4*)(xt + (k + kk) * 32);
            float wv = wk[kk];
            #pragma unroll
            for (int q = 0; q < 8; ++q) {
                float4 xv = xr[q];
                acc[q*4+0] += wv * xv.x;
                acc[q*4+1] += wv * xv.y;
                acc[q*4+2] += wv * xv.z;
                acc[q*4+3] += wv * xv.w;
            }
        }
    }
    const float bdv = bd[c];
    u32* dst = (u32*)(fd + ((size_t)b * C_ + c) * 256 + tile * 32);
    #pragma unroll
    for (int m = 0; m < 16; ++m) {
        u32 lo = f2bf(acc[2*m] + bdv);
        u32 hi = f2bf(acc[2*m+1] + bdv);
        dst[m] = lo | (hi << 16);
    }
}

__global__ __launch_bounds__(256) void k_attn_fe1(
    const float* __restrict__ x, const float* __restrict__ fb,
    const float* __restrict__ fc, const u16* __restrict__ fd,
    const float* __restrict__ alpha, u16* __restrict__ xf2)
{
    if (alpha[0] == 0.f) return;
    __shared__ __align__(16) float smem[12800];
    float* fbt = smem;
    float* fct = smem + 512;
    float* S   = smem + 8704;
    float* attnT = smem + 512;
    const int tile = blockIdx.x;
    const int b = blockIdx.y, t = threadIdx.x;
    #pragma unroll
    for (int s = 0; s < 2; ++s) {
        int j = t + 256 * s;
        int o = j >> 4, l = j & 15;
        fbt[o * 16 + l] = fb[((size_t)b * C8_ + o) * 256 + tile * 16 + l];
    }
    #pragma unroll
    for (int s = 0; s < 32; ++s) {
        int j = t + 256 * s;
        int o = j >> 8, m = j & 255;
        fct[o * 256 + m] = fc[((size_t)b * C8_ + o) * 256 + m];
    }
    __syncthreads();
    {
        const int lane = t & 63, wv = t >> 6;
        float acc[4][4];
        #pragma unroll
        for (int i = 0; i < 4; ++i)
            #pragma unroll
            for (int j = 0; j < 4; ++j) acc[i][j] = 0.f;
        for (int o = 0; o < 32; ++o) {
            float cv[4];
            #pragma unroll
            for (int j = 0; j < 4; ++j) cv[j] = fct[o * 256 + lane + 64 * j];
            #pragma unroll
            for (int i = 0; i < 4; ++i) {
                float a = fbt[o * 16 + wv * 4 + i];
                #pragma unroll
                for (int j = 0; j < 4; ++j) acc[i][j] += a * cv[j];
            }
        }
        #pragma unroll
        for (int i = 0; i < 4; ++i)
            #pragma unroll
            for (int j = 0; j < 4; ++j)
                S[(wv * 4 + i) * 256 + lane + 64 * j] = acc[i][j];
    }
    __syncthreads();
    {
        const int r = t >> 4, k = t & 15;
        float vals[16];
        float mx = -1e30f;
        #pragma unroll
        for (int j = 0; j < 16; ++j) {
            vals[j] = S[r * 256 + k + 16 * j];
            mx = fmaxf(mx, vals[j]);
        }
        mx = fmaxf(mx, __shfl_xor(mx, 1, 16));
        mx = fmaxf(mx, __shfl_xor(mx, 2, 16));
        mx = fmaxf(mx, __shfl_xor(mx, 4, 16));
        mx = fmaxf(mx, __shfl_xor(mx, 8, 16));
        float sum = 0.f;
        #pragma unroll
        for (int j = 0; j < 16; ++j) { vals[j] = __expf(vals[j] - mx); sum += vals[j]; }
        sum += __shfl_xor(sum, 1, 16);
        sum += __shfl_xor(sum, 2, 16);
        sum += __shfl_xor(sum, 4, 16);
        sum += __shfl_xor(sum, 8, 16);
        const float inv = 1.0f / sum;
        #pragma unroll
        for (int j = 0; j < 16; ++j)
            attnT[(k + 16 * j) * 16 + r] = vals[j] * inv;
    }
    __syncthreads();
    const int c = t;
    float acc[16];
    #pragma unroll
    for (int i = 0; i < 16; ++i) acc[i] = 0.f;
    const u16* fdrow = fd + ((size_t)b * C_ + c) * 256;
    for (int m = 0; m < 256; m += 4) {
        uint2 p = *(const uint2*)(fdrow + m);
        float wm[4] = { bf2f(p.x & 0xffffu), bf2f(p.x >> 16),
                        bf2f(p.y & 0xffffu), bf2f(p.y >> 16) };
        #pragma unroll
        for (int mm = 0; mm < 4; ++mm) {
            const float4* ar = (const float4*)(attnT + (m + mm) * 16);
            float wv = wm[mm];
            #pragma unroll
            for (int q = 0; q < 4; ++q) {
                float4 av = ar[q];
                acc[q*4+0] += wv * av.x;
                acc[q*4+1] += wv * av.y;
                acc[q*4+2] += wv * av.z;
                acc[q*4+3] += wv * av.w;
            }
        }
    }
    const float al = alpha[0];
    const int n = b >> 6, ph = (b >> 3) & 7, pw = b & 7;
    const int l2 = ph * 8 + pw;
    const float* xb = x + (size_t)n * C_ * HW_ + (size_t)c * HW_;
    #pragma unroll
    for (int i = 0; i < 16; ++i) {
        int l1 = tile * 16 + i;
        int qh = l1 >> 4, qw = l1 & 15;
        float xv = xb[(qh * 8 + ph) * W_ + (qw * 8 + pw)];
        size_t b2 = (size_t)n * 256 + qh * 16 + qw;
        xf2[(b2 * 64 + l2) * 256 + c] = f2bf(al * acc[i] + xv);
    }
}

// ---------------------------------------------------------------------------
// K6: fully-fused PAM2 per b2. MFMA for fbc2 / S / fd2 / fe2.
// xf2 bf16 [b2][64 l][256 c]; out fp32 NCHW.
// LDS (u16 units): fdslab [256][72] @0, fbcT [64][72] @18432, attn [64][72] @23040
// out-staging overlays fdslab as float [64][133].
// ---------------------------------------------------------------------------
#define FDSLAB 0
#define FBCT   18432
#define ATTN   23040

__global__ __launch_bounds__(256) void k_pam2_fused(
    const u16* __restrict__ xf2, const u16* __restrict__ Wbc2,
    const u16* __restrict__ Wd2, const float* __restrict__ bb2,
    const float* __restrict__ bc2, const float* __restrict__ bd2,
    const float* __restrict__ alpha2, float* __restrict__ out)
{
    __shared__ __align__(16) u16 lds[27648];
    const int b2 = blockIdx.x;
    const int n = b2 >> 8, qh = (b2 >> 4) & 15, qw = b2 & 15;
    const int t = threadIdx.x;
    const int w = t >> 6, lane = t & 63;
    const int q = lane >> 4, i = lane & 15;
    const int ls = w * 16;   // wave's l-strip (phases 1,3,6) / c-strip base uses cs
    const u16* xrow0 = xf2 + (size_t)b2 * 64 * 256;

    // ---- phase 1: fbc2[o][l] = Wbc2 @ xf2^T (M=64 o, N=16 l per wave, K=256)
    f32x4_t acc1[4];
    #pragma unroll
    for (int mt = 0; mt < 4; ++mt) acc1[mt] = (f32x4_t){0.f,0.f,0.f,0.f};
    for (int ks = 0; ks < 8; ++ks) {
        int kb = ks * 32 + q * 8;
        bf16x8_t bfr = ld_frag(xrow0 + (size_t)(ls + i) * 256 + kb);
        #pragma unroll
        for (int mt = 0; mt < 4; ++mt) {
            bf16x8_t afr = ld_frag(Wbc2 + (mt * 16 + i) * 256 + kb);
            acc1[mt] = __builtin_amdgcn_mfma_f32_16x16x32_bf16(afr, bfr, acc1[mt], 0, 0, 0);
        }
    }
    // bias + transpose-store fbcT[l][o]
    #pragma unroll
    for (int mt = 0; mt < 4; ++mt) {
        #pragma unroll
        for (int r = 0; r < 4; ++r) {
            int o = mt * 16 + q * 4 + r;
            float bv = (o < 32) ? bb2[o] : bc2[o - 32];
            lds[FBCT + (ls + i) * 72 + o] = f2bf(acc1[mt][r] + bv);
        }
    }
    __syncthreads();

    // ---- phase 3: S[l][m] = fbT @ fcT^T (M=16 l, N=64 m, K=32 o)
    f32x4_t accS[4];
    #pragma unroll
    for (int nt = 0; nt < 4; ++nt) accS[nt] = (f32x4_t){0.f,0.f,0.f,0.f};
    {
        bf16x8_t afr = ld_frag(&lds[FBCT + (ls + i) * 72 + q * 8]);
        #pragma unroll
        for (int nt = 0; nt < 4; ++nt) {
            bf16x8_t bfr = ld_frag(&lds[FBCT + (nt * 16 + i) * 72 + 32 + q * 8]);
            accS[nt] = __builtin_amdgcn_mfma_f32_16x16x32_bf16(afr, bfr, accS[nt], 0, 0, 0);
        }
    }
    // ---- phase 4: softmax rows -> attn bf16 [l][m]
    #pragma unroll
    for (int r = 0; r < 4; ++r) {
        int l = ls + q * 4 + r;
        float mx = accS[0][r];
        #pragma unroll
        for (int nt = 1; nt < 4; ++nt) mx = fmaxf(mx, accS[nt][r]);
        mx = fmaxf(mx, __shfl_xor(mx, 1));
        mx = fmaxf(mx, __shfl_xor(mx, 2));
        mx = fmaxf(mx, __shfl_xor(mx, 4));
        mx = fmaxf(mx, __shfl_xor(mx, 8));
        float e[4], sum = 0.f;
        #pragma unroll
        for (int nt = 0; nt < 4; ++nt) { e[nt] = __expf(accS[nt][r] - mx); sum += e[nt]; }
        sum += __shfl_xor(sum, 1);
        sum += __shfl_xor(sum, 2);
        sum += __shfl_xor(sum, 4);
        sum += __shfl_xor(sum, 8);
        float inv = 1.0f / sum;
        #pragma unroll
        for (int nt = 0; nt < 4; ++nt)
            lds[ATTN + l * 72 + nt * 16 + i] = f2bf(e[nt] * inv);
    }

    // ---- phase 5: fd2[c][m] = Wd2 @ xf2^T (per wave M=64 c, N=64 m, K=256)
    {
        const int cs = w * 64;
        f32x4_t acc2[4][4];
        #pragma unroll
        for (int mt = 0; mt < 4; ++mt)
            #pragma unroll
            for (int nt = 0; nt < 4; ++nt) acc2[mt][nt] = (f32x4_t){0.f,0.f,0.f,0.f};
        for (int ks = 0; ks < 8; ++ks) {
            int kb = ks * 32 + q * 8;
            bf16x8_t bfr[4];
            #pragma unroll
            for (int nt = 0; nt < 4; ++nt)
                bfr[nt] = ld_frag(xrow0 + (size_t)(nt * 16 + i) * 256 + kb);
            #pragma unroll
            for (int mt = 0; mt < 4; ++mt) {
                bf16x8_t afr = ld_frag(Wd2 + (size_t)(cs + mt * 16 + i) * 256 + kb);
                #pragma unroll
                for (int nt = 0; nt < 4; ++nt)
                    acc2[mt][nt] = __builtin_amdgcn_mfma_f32_16x16x32_bf16(afr, bfr[nt], acc2[mt][nt], 0, 0, 0);
            }
        }
        #pragma unroll
        for (int mt = 0; mt < 4; ++mt) {
            #pragma unroll
            for (int r = 0; r < 4; ++r) {
                int c = cs + mt * 16 + q * 4 + r;
                float bv = bd2[c];
                #pragma unroll
                for (int nt = 0; nt < 4; ++nt)
                    lds[FDSLAB + c * 72 + nt * 16 + i] = f2bf(acc2[mt][nt][r] + bv);
            }
        }
    }
    __syncthreads();

    // ---- phase 6: fe[l][c] = attn @ fd^T (per wave M=16 l, N=256 c, K=64 m)
    f32x4_t accE[16];
    #pragma unroll
    for (int nt = 0; nt < 16; ++nt) accE[nt] = (f32x4_t){0.f,0.f,0.f,0.f};
    #pragma unroll
    for (int ks = 0; ks < 2; ++ks) {
        int kb = ks * 32 + q * 8;
        bf16x8_t afr = ld_frag(&lds[ATTN + (ls + i) * 72 + kb]);
        #pragma unroll
        for (int nt = 0; nt < 16; ++nt) {
            bf16x8_t bfr = ld_frag(&lds[FDSLAB + (nt * 16 + i) * 72 + kb]);
            accE[nt] = __builtin_amdgcn_mfma_f32_16x16x32_bf16(afr, bfr, accE[nt], 0, 0, 0);
        }
    }

    // ---- phase 7: residual + write out (fp32 NCHW) via LDS staging
    const float al = alpha2[0];
    float vals[64];
    #pragma unroll
    for (int nt = 0; nt < 16; ++nt) {
        #pragma unroll
        for (int r = 0; r < 4; ++r) {
            int l = ls + q * 4 + r;
            int c = nt * 16 + i;
            float xv = bf2f(xrow0[(size_t)l * 256 + c]);
            vals[nt * 4 + r] = al * accE[nt][r] + xv;
        }
    }
    float* stg = (float*)lds;   // overlays fdslab region: [64][133] floats
    for (int h = 0; h < 2; ++h) {
        __syncthreads();
        #pragma unroll
        for (int nt = h * 8; nt < h * 8 + 8; ++nt) {
            #pragma unroll
            for (int r = 0; r < 4; ++r) {
                int l = ls + q * 4 + r;
                int cc = nt * 16 + i - h * 128;
                stg[l * 133 + cc] = vals[nt * 4 + r];
            }
        }
        __syncthreads();
        int ph = lane >> 3, pw = lane & 7;
        for (int j = 0; j < 32; ++j) {
            int c = h * 128 + w * 32 + j;
            float v = stg[lane * 133 + (c - h * 128)];
            out[(((size_t)n * 256 + c) * 128 + qh * 8 + ph) * 128 + qw * 8 + pw] = v;
        }
    }
}

extern "C" void kernel_launch(void* const* d_in, const int* in_sizes, int n_in,
                              void* d_out, int out_size, void* d_ws, size_t ws_size,
                              hipStream_t stream)
{
    const float* x   = (const float*)d_in[0];
    const float* Wb1 = (const float*)d_in[1];
    const float* bb1 = (const float*)d_in[2];
    const float* Wc1 = (const float*)d_in[3];
    const float* bc1 = (const float*)d_in[4];
    const float* Wd1 = (const float*)d_in[5];
    const float* bd1 = (const float*)d_in[6];
    const float* a1  = (const float*)d_in[7];
    const float* Wb2 = (const float*)d_in[8];
    const float* bb2 = (const float*)d_in[9];
    const float* Wc2 = (const float*)d_in[10];
    const float* bc2 = (const float*)d_in[11];
    const float* Wd2 = (const float*)d_in[12];
    const float* bd2 = (const float*)d_in[13];
    const float* a2  = (const float*)d_in[14];
    (void)in_sizes; (void)n_in; (void)out_size; (void)ws_size;

    char* ws = (char*)d_ws;
    u16*   xf1  = (u16*)(ws + WS_XF1);
    u16*   xf2  = (u16*)(ws + WS_XF2);
    u16*   Wbc2 = (u16*)(ws + WS_WBC2);
    u16*   Wd2b = (u16*)(ws + WS_WD2);
    float* fb1  = (float*)(ws + WS_FB1);
    float* fc1  = (float*)(ws + WS_FC1);
    u16*   fd1  = (u16*)(ws + WS_FD1);
    float* out  = (float*)d_out;

    k_wpack<<<dim3(320), 256, 0, stream>>>(Wb2, Wc2, Wd2, Wbc2, Wd2b);
    k_gather<<<dim3(2048), 256, 0, stream>>>(x, a1, xf1, xf2);
    // PAM1 general path (early-exits when alpha1 == 0, which holds for this input)
    k_fbfc1<<<dim3(8, 512), 256, 0, stream>>>(x, Wb1, bb1, Wc1, bc1, fb1, fc1, a1);
    k_fd1<<<dim3(8, 512), 256, 0, stream>>>(x, Wd1, bd1, fd1, a1);
    k_attn_fe1<<<dim3(16, 512), 256, 0, stream>>>(x, fb1, fc1, fd1, a1, xf2);
    // PAM2 fused
    k_pam2_fused<<<dim3(2048), 256, 0, stream>>>(xf2, Wbc2, Wd2b, bb2, bc2, bd2, a2, out);
}